// Round 5
// baseline (716.483 us; speedup 1.0000x reference)
//
#include <hip/hip_runtime.h>
#include <cstdint>

#define CONF_THRES 0.25f
#define IOU_THRES  0.45f
#define MAX_DET    300
#define K_TOP      8192
#define NA         102000
#define NCLS       80
#define ROWLEN     85
#define CAP        32640
#define NPLANE     32
#define CCH        32

typedef unsigned long long u64;
typedef unsigned int u32;

// ---------------- kernel 1: wave-per-anchor scores -> sortable keys + histogram ----
// Histogram goes to 32 replicated planes (plane = blockIdx&31, plane-major layout) to
// cut same-line L2 atomic serialization ~32x. Planes live in the mask region (free
// space: mask_kernel overwrites it only after cutoff consumed the histogram).
__global__ __launch_bounds__(256) void score_key_kernel(const float* __restrict__ preds,
        u64* __restrict__ keys, u32* __restrict__ histP) {
#pragma clang fp contract(off)
    int lane = threadIdx.x & 63;
    int i = blockIdx.x * 4 + (threadIdx.x >> 6);     // 4 waves/block, 1 anchor/wave
    if (i >= NA) return;
    const float* p = preds + (size_t)i * ROWLEN;
    float v0 = p[lane];                               // offsets 0..63
    float v1 = (lane < ROWLEN - 64) ? p[64 + lane] : 0.0f; // offsets 64..84
    float obj = __shfl(v0, 4);
    float m = (lane >= 5) ? v0 : 0.0f;                // classes 0..58 (scores >= 0)
    m = fmaxf(m, (lane < 21) ? v1 : 0.0f);            // classes 59..79
    for (int off = 32; off; off >>= 1) m = fmaxf(m, __shfl_xor(m, off));
    if (lane == 0) {
        float score = (obj > CONF_THRES) ? m * obj : 0.0f;
        u32 sb = __float_as_uint(score);              // score >= 0: order-preserving bits
        keys[i] = ((u64)sb << 32) | (u32)(~(u32)i);   // tie-break: smaller index wins
        if (sb != 0u)
            atomicAdd(&histP[((u32)blockIdx.x & (NPLANE - 1u)) * 65536u + (sb >> 16)], 1u);
    }
}

// ---------------- kernel 1b: fold 32 histogram planes -> sumhist ----------------
__global__ __launch_bounds__(256) void reduce_hist_kernel(const u32* __restrict__ histP,
        u32* __restrict__ sumhist) {
    int bin = blockIdx.x * 256 + threadIdx.x;         // grid 256 -> 65536 bins
    u32 s = 0;
#pragma unroll
    for (int r = 0; r < NPLANE; ++r) s += histP[r * 65536 + bin];
    sumhist[bin] = s;
}

// ---------------- kernel 2: find threshold bucket for top-K ----------------
__global__ __launch_bounds__(1024) void cutoff_kernel(const u32* __restrict__ hist,
        u32* __restrict__ meta) {
    __shared__ u32 chunk[1024];
    int t = threadIdx.x;
    u32 s = 0;
    for (int b = t * 64; b < t * 64 + 64; ++b) s += hist[b];
    chunk[t] = s;
    __syncthreads();
    if (t == 0) {
        u32 acc = 0;
        int cb = -1;
        for (int c = 1023; c >= 0; --c) {
            if (acc + chunk[c] >= (u32)K_TOP) { cb = c; break; }
            acc += chunk[c];
        }
        u32 thresh = 0;
        if (cb >= 0) {
            for (int b = cb * 64 + 63; b >= cb * 64; --b) {
                if (acc + hist[b] >= (u32)K_TOP) { thresh = (u32)b << 16; break; }
                acc += hist[b];
            }
        }
        meta[1] = thresh;   // meta[0] is the compact counter (zeroed by memset)
    }
}

// ---------------- kernel 3: compact candidates above threshold ----------------
__global__ __launch_bounds__(256) void compact_kernel(const u64* __restrict__ keys,
        u32* __restrict__ meta, u64* __restrict__ comp) {
    __shared__ u32 woff[4];
    __shared__ u32 bbase;
    int i = blockIdx.x * 256 + threadIdx.x;
    int wid = threadIdx.x >> 6, lane = threadIdx.x & 63;
    u64 key = (i < NA) ? keys[i] : 0ull;
    u32 sb = (u32)(key >> 32);
    u32 th = meta[1];
    bool take = (i < NA) && (sb != 0u) && (sb >= th);
    u64 bal = __ballot(take);
    if (lane == 0) woff[wid] = (u32)__popcll(bal);
    __syncthreads();
    if (threadIdx.x == 0) {
        u32 t0 = woff[0], t1 = woff[1], t2 = woff[2], t3 = woff[3];
        bbase = atomicAdd(&meta[0], t0 + t1 + t2 + t3);
        woff[0] = 0; woff[1] = t0; woff[2] = t0 + t1; woff[3] = t0 + t1 + t2;
    }
    __syncthreads();
    if (take) {
        u32 pos = bbase + woff[wid] + (u32)__popcll(bal & ((1ull << lane) - 1ull));
        if (pos < CAP) comp[pos] = key;
    }
}

// ---------------- kernel 4: rank-by-counting -> sorted top-K keys ----------------
__global__ __launch_bounds__(256) void rank_kernel(const u64* __restrict__ comp,
        const u32* __restrict__ meta, u64* __restrict__ sorted) {
    __shared__ u64 tile[1024];
    u32 cnt = meta[0];
    int n = (int)(cnt < (u32)CAP ? cnt : (u32)CAP);
    if (blockIdx.x * 256 >= n) return;               // whole-block early exit (uniform)
    int tid = blockIdx.x * 256 + threadIdx.x;
    u64 key = (tid < n) ? comp[tid] : 0ull;
    u32 rank = 0;
    for (int base = 0; base < n; base += 1024) {
        int lim = (n - base < 1024) ? (n - base) : 1024;
        __syncthreads();
        for (int k = threadIdx.x; k < lim; k += 256) tile[k] = comp[base + k];
        __syncthreads();
        if (tid < n) {
            for (int j = 0; j < lim; ++j) rank += (tile[j] > key) ? 1u : 0u;
        }
    }
    if (tid < n && rank < (u32)K_TOP) sorted[rank] = key;  // keys unique -> perm
}

// ---------------- kernel 5: wave-per-anchor gather of boxes/classes/scores ---------
__global__ __launch_bounds__(256) void gather_kernel(const u64* __restrict__ sorted,
        const float* __restrict__ preds, float* __restrict__ boxes,
        float* __restrict__ scores, float* __restrict__ classes) {
#pragma clang fp contract(off)
    int lane = threadIdx.x & 63;
    int i = blockIdx.x * 4 + (threadIdx.x >> 6);     // i in [0, 8192)
    u64 key = sorted[i];
    u32 sb = (u32)(key >> 32);
    float score = __uint_as_float(sb);
    if (score > 0.0f) {                               // uniform across the wave
        u32 idx = ~(u32)(key & 0xffffffffull);
        const float* p = preds + (size_t)idx * ROWLEN;
        float v0 = p[lane];
        float v1 = (lane < ROWLEN - 64) ? p[64 + lane] : 0.0f;
        float obj = __shfl(v0, 4);
        // argmax over products, first-index tie-break: key=(bits<<8)|(255-cls), max
        u64 kb = 0;
        if (lane >= 5) {
            float q = v0 * obj;                       // class lane-5
            kb = ((u64)__float_as_uint(q) << 8) | (u32)(255 - (lane - 5));
        }
        if (lane < 21) {
            float q = v1 * obj;                       // class 59+lane
            u64 kb2 = ((u64)__float_as_uint(q) << 8) | (u32)(255 - (59 + lane));
            if (kb2 > kb) kb = kb2;
        }
        for (int off = 32; off; off >>= 1) {
            u64 o = __shfl_xor(kb, off);
            if (o > kb) kb = o;
        }
        u32 cls = 255u - (u32)(kb & 0xffull);
        float x = __shfl(v0, 0), y = __shfl(v0, 1);
        float w = __shfl(v0, 2), h = __shfl(v0, 3);
        if (lane == 0) {
            boxes[i * 4 + 0] = y - h * 0.5f;          // ymin
            boxes[i * 4 + 1] = x - w * 0.5f;          // xmin
            boxes[i * 4 + 2] = y + h * 0.5f;          // ymax
            boxes[i * 4 + 3] = x + w * 0.5f;          // xmax
            scores[i] = score;
            classes[i] = (float)cls;
        }
    } else if (lane == 0) {
        boxes[i * 4 + 0] = 0.0f; boxes[i * 4 + 1] = 0.0f;
        boxes[i * 4 + 2] = 0.0f; boxes[i * 4 + 3] = 0.0f;
        scores[i] = 0.0f;
        classes[i] = 0.0f;
    }
}

// ---------------- kernel 6: suppression bitmask (iou > thres, j > i) ----------------
__global__ __launch_bounds__(256) void mask_kernel(const float* __restrict__ boxes,
        u64* __restrict__ mask) {
#pragma clang fp contract(off)
    __shared__ float4 cb[64];
    int wj = blockIdx.x;                 // column word 0..127
    int i = blockIdx.y * 256 + threadIdx.x;
    int j0 = wj * 64;
    if (threadIdx.x < 64) cb[threadIdx.x] = ((const float4*)boxes)[j0 + threadIdx.x];
    __syncthreads();
    float4 bi = ((const float4*)boxes)[i];
    float area_i = (bi.z - bi.x) * (bi.w - bi.y);
    u64 bits = 0;
    if (j0 + 63 > i) {
        for (int k = 0; k < 64; ++k) {
            int j = j0 + k;
            if (j <= i) continue;
            float4 bj = cb[k];
            float area_j = (bj.z - bj.x) * (bj.w - bj.y);
            float ty = fmaxf(bi.x, bj.x);
            float tx = fmaxf(bi.y, bj.y);
            float by = fminf(bi.z, bj.z);
            float bx = fminf(bi.w, bj.w);
            float inter = fmaxf(by - ty, 0.0f) * fmaxf(bx - tx, 0.0f);
            float uni = (area_i + area_j) - inter;
            float iou = inter / (uni + 1e-9f);
            if (iou > IOU_THRES) bits |= (1ull << k);
        }
    }
    mask[(size_t)i * 128 + wj] = bits;
}

// ---------------- kernel 6b: validity words (rem init) for the scan ----------------
__global__ __launch_bounds__(256) void valid_kernel(const float* __restrict__ scores,
        u64* __restrict__ remw) {
    int w = blockIdx.x * 4 + (threadIdx.x >> 6);      // 128 waves over 32 blocks
    int lane = threadIdx.x & 63;
    u64 b = __ballot(scores[w * 64 + lane] > 0.0f);
    if (lane == 0) remw[w] = b;
}

// ---------------- kernel 7: single-wave greedy scan, chunked row prefetch ----------
// Phase-separated chunks of CCH=32 candidates: (1) pop 32 speculative indices (pure
// VALU), (2) issue all 64 row loads with no intervening uses (one latency for the
// whole batch), (3) resolve serially from registers. Avoids round-4's per-slot
// refill->use interleave that forced a waitcnt per pop.
__device__ __forceinline__ u64 bcast64(u64 v, int srclane) {
    u32 lo = (u32)__builtin_amdgcn_readlane((int)(u32)v, srclane);
    u32 hi = (u32)__builtin_amdgcn_readlane((int)(u32)(v >> 32), srclane);
    return ((u64)hi << 32) | lo;
}

__device__ __forceinline__ int ffidx(u64 w0, u64 w1) {
    u64 nz0 = __ballot(w0 != 0ull);
    if (nz0 != 0ull) {
        int w = __ffsll((unsigned long long)nz0) - 1;
        u64 word = bcast64(w0, w);
        return w * 64 + __ffsll((unsigned long long)word) - 1;
    }
    u64 nz1 = __ballot(w1 != 0ull);
    if (nz1 != 0ull) {
        int w = __ffsll((unsigned long long)nz1) - 1;
        u64 word = bcast64(w1, w);
        return (w + 64) * 64 + __ffsll((unsigned long long)word) - 1;
    }
    return -1;
}

__global__ __launch_bounds__(64) void nms_scan_kernel(const u64* __restrict__ mask,
        const u64* __restrict__ remw, const float* __restrict__ boxes,
        const float* __restrict__ scores, const float* __restrict__ classes,
        float* __restrict__ out) {
    int lane = threadIdx.x;              // exactly one wave
    u64 rem0 = remw[lane], rem1 = remw[64 + lane];
    // Speculation set: superset of rem in index order (popped bits removed,
    // suppression never applied) -> pops enumerate candidates in ascending index
    // (= descending score) order, exactly the greedy visit order.
    u64 sp0 = rem0, sp1 = rem1;
    int n = 0;
    bool done = false;
    while (!done && n < MAX_DET) {
        // phase 1: pop next CCH speculative indices (no memory access)
        int ci[CCH];
#pragma unroll
        for (int c = 0; c < CCH; ++c) {
            int t = ffidx(sp0, sp1);
            ci[c] = t;
            if (t >= 0) {
                int wt = t >> 6; u64 bt = 1ull << (t & 63);
                if (wt < 64) { if (lane == wt) sp0 &= ~bt; }
                else         { if (lane == wt - 64) sp1 &= ~bt; }
            }
        }
        if (ci[0] < 0) break;
        // phase 2: issue all row loads back-to-back (invalid slots load row 0)
        u64 q0[CCH], q1[CCH];
#pragma unroll
        for (int c = 0; c < CCH; ++c) {
            int t = (ci[c] >= 0) ? ci[c] : 0;
            const u64* row = mask + (size_t)t * 128;
            q0[c] = row[lane];
            q1[c] = row[lane + 64];
        }
        // phase 3: resolve serially from registers (no loads)
#pragma unroll
        for (int c = 0; c < CCH; ++c) {
            int i = ci[c];
            if (i < 0) { done = true; break; }
            int wi = i >> 6; u64 bit = 1ull << (i & 63);
            bool mine = (wi < 64) ? ((lane == wi) && (rem0 & bit))
                                  : ((lane == wi - 64) && (rem1 & bit));
            if (__ballot(mine) != 0ull) {            // candidate still alive -> keep
                if (lane < 4) out[n * 4 + lane] = boxes[i * 4 + lane];
                if (lane == 0) { out[1200 + n] = classes[i]; out[1500 + n] = scores[i]; }
                ++n;
                rem0 &= ~q0[c]; rem1 &= ~q1[c];
                if (wi < 64) { if (lane == wi) rem0 &= ~bit; }
                else         { if (lane == wi - 64) rem1 &= ~bit; }
                if (n >= MAX_DET) { done = true; break; }
            }
        }
    }
    // zero-fill the remaining slots (harness poisons d_out with 0xAA)
    for (int m = n; m < MAX_DET; ++m) {
        if (lane < 4) out[m * 4 + lane] = 0.0f;
        if (lane == 0) { out[1200 + m] = 0.0f; out[1500 + m] = 0.0f; }
    }
}

// ---------------- launch ----------------
extern "C" void kernel_launch(void* const* d_in, const int* in_sizes, int n_in,
                              void* d_out, int out_size, void* d_ws, size_t ws_size,
                              hipStream_t stream) {
    const float* preds = (const float*)d_in[0];
    char* ws = (char*)d_ws;

    // ws layout (bytes), total 9991104:
    //   [0, 262144)            sumhist     u32[65536]
    //   [262144, 262208)       meta        u32[16]   ([0]=counter, [1]=thresh)
    //   [262208, 263232)       remw        u64[128]
    //   [263232, 328768)       sorted      u64[8192]
    //   [328768, 1144768)      keys        u64[102000]
    //   [1144768, 1405888)     comp        u64[32640]
    //   [1405888, 1536960)     top_boxes   f32[8192*4]
    //   [1536960, 1569728)     top_scores  f32[8192]
    //   [1569728, 1602496)     top_classes f32[8192]
    //   [1602496, 9991104)     mask        u64[8192*128]  (8 MB; doubles as the
    //                                      32-plane histogram before mask_kernel)
    u32*   sumhist = (u32*)(ws + 0);
    u32*   meta    = (u32*)(ws + 262144);
    u64*   remw    = (u64*)(ws + 262208);
    u64*   sorted  = (u64*)(ws + 263232);
    u64*   keys    = (u64*)(ws + 328768);
    u64*   comp    = (u64*)(ws + 1144768);
    float* tboxes  = (float*)(ws + 1405888);
    float* tscores = (float*)(ws + 1536960);
    float* tclass  = (float*)(ws + 1569728);
    u64*   mask    = (u64*)(ws + 1602496);
    u32*   histP   = (u32*)(ws + 1602496);           // aliases mask region
    float* out     = (float*)d_out;

    hipMemsetAsync(ws, 0, 328768, stream);           // sumhist+meta+remw+sorted
    hipMemsetAsync(histP, 0, (size_t)NPLANE * 65536 * 4, stream);  // hist planes (8 MB)

    score_key_kernel<<<(NA + 3) / 4, 256, 0, stream>>>(preds, keys, histP);
    reduce_hist_kernel<<<256, 256, 0, stream>>>(histP, sumhist);
    cutoff_kernel<<<1, 1024, 0, stream>>>(sumhist, meta);
    compact_kernel<<<(NA + 255) / 256, 256, 0, stream>>>(keys, meta, comp);
    rank_kernel<<<(CAP + 255) / 256, 256, 0, stream>>>(comp, meta, sorted);
    gather_kernel<<<K_TOP / 4, 256, 0, stream>>>(sorted, preds, tboxes, tscores, tclass);
    mask_kernel<<<dim3(128, K_TOP / 256), 256, 0, stream>>>(tboxes, mask);
    valid_kernel<<<32, 256, 0, stream>>>(tscores, remw);
    nms_scan_kernel<<<1, 64, 0, stream>>>(mask, remw, tboxes, tscores, tclass, out);
}

// Round 6
// 579.122 us; speedup vs baseline: 1.2372x; 1.2372x over previous
//
#include <hip/hip_runtime.h>
#include <cstdint>

#define CONF_THRES 0.25f
#define IOU_THRES  0.45f
#define MAX_DET    300
#define K_TOP      8192
#define NA         102000
#define NCLS       80
#define ROWLEN     85
#define CAP        32640
#define NPLANE     32
#define CCH        32

typedef unsigned long long u64;
typedef unsigned int u32;

// ---------------- kernel 1: wave-per-anchor scores -> sortable keys + histogram ----
// Histogram goes to 32 replicated planes (plane = blockIdx&31, plane-major layout) to
// cut same-line L2 atomic serialization ~32x. Planes live in the mask region (free
// space: mask_kernel overwrites it only after cutoff consumed the histogram).
__global__ __launch_bounds__(256) void score_key_kernel(const float* __restrict__ preds,
        u64* __restrict__ keys, u32* __restrict__ histP) {
#pragma clang fp contract(off)
    int lane = threadIdx.x & 63;
    int i = blockIdx.x * 4 + (threadIdx.x >> 6);     // 4 waves/block, 1 anchor/wave
    if (i >= NA) return;
    const float* p = preds + (size_t)i * ROWLEN;
    float v0 = p[lane];                               // offsets 0..63
    float v1 = (lane < ROWLEN - 64) ? p[64 + lane] : 0.0f; // offsets 64..84
    float obj = __shfl(v0, 4);
    float m = (lane >= 5) ? v0 : 0.0f;                // classes 0..58 (scores >= 0)
    m = fmaxf(m, (lane < 21) ? v1 : 0.0f);            // classes 59..79
    for (int off = 32; off; off >>= 1) m = fmaxf(m, __shfl_xor(m, off));
    if (lane == 0) {
        float score = (obj > CONF_THRES) ? m * obj : 0.0f;
        u32 sb = __float_as_uint(score);              // score >= 0: order-preserving bits
        keys[i] = ((u64)sb << 32) | (u32)(~(u32)i);   // tie-break: smaller index wins
        if (sb != 0u)
            atomicAdd(&histP[((u32)blockIdx.x & (NPLANE - 1u)) * 65536u + (sb >> 16)], 1u);
    }
}

// ---------------- kernel 1b: fold 32 histogram planes -> sumhist ----------------
__global__ __launch_bounds__(256) void reduce_hist_kernel(const u32* __restrict__ histP,
        u32* __restrict__ sumhist) {
    int bin = blockIdx.x * 256 + threadIdx.x;         // grid 256 -> 65536 bins
    u32 s = 0;
#pragma unroll
    for (int r = 0; r < NPLANE; ++r) s += histP[r * 65536 + bin];
    sumhist[bin] = s;
}

// ---------------- kernel 2: find threshold bucket for top-K (parallel scan) --------
// Replaces the serial thread-0 walk (1024 dependent LDS reads ~ 60us) with a
// Hillis-Steele suffix scan (10 steps) + one-wave shuffle suffix scan for the fine
// 64-bin pass. Selection is bitwise identical: cb = max c with suf[c] >= K,
// bstar = max b with sufb(b)+above >= K.
__global__ __launch_bounds__(1024) void cutoff_kernel(const u32* __restrict__ hist,
        u32* __restrict__ meta) {
    __shared__ u32 suf[1024];
    __shared__ int cbs;
    __shared__ u32 above_s;
    int t = threadIdx.x;
    u32 s = 0;
    const u32* hb = hist + t * 64;
    for (int b = 0; b < 64; ++b) s += hb[b];
    suf[t] = s;
    if (t == 0) { cbs = -1; above_s = 0; }
    __syncthreads();
    for (int off = 1; off < 1024; off <<= 1) {
        u32 add = (t + off < 1024) ? suf[t + off] : 0u;
        __syncthreads();
        suf[t] += add;
        __syncthreads();
    }
    u32 st = suf[t];
    u32 stn = (t < 1023) ? suf[t + 1] : 0u;
    if (st >= (u32)K_TOP && stn < (u32)K_TOP) {       // at most one thread
        cbs = t;
        above_s = stn;                                 // sum of chunks above cb
    }
    __syncthreads();
    int cb = cbs;
    if (t < 64) {                                      // wave 0 does the fine pass
        u32 thresh = 0;
        if (cb >= 0) {
            u32 above = above_s;
            u32 v = hist[cb * 64 + t];
            // wave suffix-inclusive scan: v = sum_{b >= t} hist[cb*64+b]
            for (int off = 1; off < 64; off <<= 1) {
                u32 o = __shfl_down(v, off);
                if (t + off < 64) v += o;
            }
            u64 bal = __ballot(v + above >= (u32)K_TOP);   // nonzero: suf[cb] >= K
            int bstar = 63 - __builtin_clzll((unsigned long long)bal);
            thresh = ((u32)(cb * 64 + bstar)) << 16;
        }
        if (t == 0) meta[1] = thresh;                  // meta[0] zeroed by memset
    }
}

// ---------------- kernel 3: compact candidates above threshold ----------------
__global__ __launch_bounds__(256) void compact_kernel(const u64* __restrict__ keys,
        u32* __restrict__ meta, u64* __restrict__ comp) {
    __shared__ u32 woff[4];
    __shared__ u32 bbase;
    int i = blockIdx.x * 256 + threadIdx.x;
    int wid = threadIdx.x >> 6, lane = threadIdx.x & 63;
    u64 key = (i < NA) ? keys[i] : 0ull;
    u32 sb = (u32)(key >> 32);
    u32 th = meta[1];
    bool take = (i < NA) && (sb != 0u) && (sb >= th);
    u64 bal = __ballot(take);
    if (lane == 0) woff[wid] = (u32)__popcll(bal);
    __syncthreads();
    if (threadIdx.x == 0) {
        u32 t0 = woff[0], t1 = woff[1], t2 = woff[2], t3 = woff[3];
        bbase = atomicAdd(&meta[0], t0 + t1 + t2 + t3);
        woff[0] = 0; woff[1] = t0; woff[2] = t0 + t1; woff[3] = t0 + t1 + t2;
    }
    __syncthreads();
    if (take) {
        u32 pos = bbase + woff[wid] + (u32)__popcll(bal & ((1ull << lane) - 1ull));
        if (pos < CAP) comp[pos] = key;
    }
}

// ---------------- kernel 4: rank-by-counting -> sorted top-K keys ----------------
__global__ __launch_bounds__(256) void rank_kernel(const u64* __restrict__ comp,
        const u32* __restrict__ meta, u64* __restrict__ sorted) {
    __shared__ u64 tile[1024];
    u32 cnt = meta[0];
    int n = (int)(cnt < (u32)CAP ? cnt : (u32)CAP);
    if (blockIdx.x * 256 >= n) return;               // whole-block early exit (uniform)
    int tid = blockIdx.x * 256 + threadIdx.x;
    u64 key = (tid < n) ? comp[tid] : 0ull;
    u32 rank = 0;
    for (int base = 0; base < n; base += 1024) {
        int lim = (n - base < 1024) ? (n - base) : 1024;
        __syncthreads();
        for (int k = threadIdx.x; k < lim; k += 256) tile[k] = comp[base + k];
        __syncthreads();
        if (tid < n) {
            for (int j = 0; j < lim; ++j) rank += (tile[j] > key) ? 1u : 0u;
        }
    }
    if (tid < n && rank < (u32)K_TOP) sorted[rank] = key;  // keys unique -> perm
}

// ---------------- kernel 5: wave-per-anchor gather of boxes/classes/scores ---------
__global__ __launch_bounds__(256) void gather_kernel(const u64* __restrict__ sorted,
        const float* __restrict__ preds, float* __restrict__ boxes,
        float* __restrict__ scores, float* __restrict__ classes) {
#pragma clang fp contract(off)
    int lane = threadIdx.x & 63;
    int i = blockIdx.x * 4 + (threadIdx.x >> 6);     // i in [0, 8192)
    u64 key = sorted[i];
    u32 sb = (u32)(key >> 32);
    float score = __uint_as_float(sb);
    if (score > 0.0f) {                               // uniform across the wave
        u32 idx = ~(u32)(key & 0xffffffffull);
        const float* p = preds + (size_t)idx * ROWLEN;
        float v0 = p[lane];
        float v1 = (lane < ROWLEN - 64) ? p[64 + lane] : 0.0f;
        float obj = __shfl(v0, 4);
        // argmax over products, first-index tie-break: key=(bits<<8)|(255-cls), max
        u64 kb = 0;
        if (lane >= 5) {
            float q = v0 * obj;                       // class lane-5
            kb = ((u64)__float_as_uint(q) << 8) | (u32)(255 - (lane - 5));
        }
        if (lane < 21) {
            float q = v1 * obj;                       // class 59+lane
            u64 kb2 = ((u64)__float_as_uint(q) << 8) | (u32)(255 - (59 + lane));
            if (kb2 > kb) kb = kb2;
        }
        for (int off = 32; off; off >>= 1) {
            u64 o = __shfl_xor(kb, off);
            if (o > kb) kb = o;
        }
        u32 cls = 255u - (u32)(kb & 0xffull);
        float x = __shfl(v0, 0), y = __shfl(v0, 1);
        float w = __shfl(v0, 2), h = __shfl(v0, 3);
        if (lane == 0) {
            boxes[i * 4 + 0] = y - h * 0.5f;          // ymin
            boxes[i * 4 + 1] = x - w * 0.5f;          // xmin
            boxes[i * 4 + 2] = y + h * 0.5f;          // ymax
            boxes[i * 4 + 3] = x + w * 0.5f;          // xmax
            scores[i] = score;
            classes[i] = (float)cls;
        }
    } else if (lane == 0) {
        boxes[i * 4 + 0] = 0.0f; boxes[i * 4 + 1] = 0.0f;
        boxes[i * 4 + 2] = 0.0f; boxes[i * 4 + 3] = 0.0f;
        scores[i] = 0.0f;
        classes[i] = 0.0f;
    }
}

// ---------------- kernel 6: suppression bitmask (iou > thres, j > i) ----------------
__global__ __launch_bounds__(256) void mask_kernel(const float* __restrict__ boxes,
        u64* __restrict__ mask) {
#pragma clang fp contract(off)
    __shared__ float4 cb[64];
    int wj = blockIdx.x;                 // column word 0..127
    int i = blockIdx.y * 256 + threadIdx.x;
    int j0 = wj * 64;
    if (threadIdx.x < 64) cb[threadIdx.x] = ((const float4*)boxes)[j0 + threadIdx.x];
    __syncthreads();
    float4 bi = ((const float4*)boxes)[i];
    float area_i = (bi.z - bi.x) * (bi.w - bi.y);
    u64 bits = 0;
    if (j0 + 63 > i) {
        for (int k = 0; k < 64; ++k) {
            int j = j0 + k;
            if (j <= i) continue;
            float4 bj = cb[k];
            float area_j = (bj.z - bj.x) * (bj.w - bj.y);
            float ty = fmaxf(bi.x, bj.x);
            float tx = fmaxf(bi.y, bj.y);
            float by = fminf(bi.z, bj.z);
            float bx = fminf(bi.w, bj.w);
            float inter = fmaxf(by - ty, 0.0f) * fmaxf(bx - tx, 0.0f);
            float uni = (area_i + area_j) - inter;
            float iou = inter / (uni + 1e-9f);
            if (iou > IOU_THRES) bits |= (1ull << k);
        }
    }
    mask[(size_t)i * 128 + wj] = bits;
}

// ---------------- kernel 6b: validity words (rem init) for the scan ----------------
__global__ __launch_bounds__(256) void valid_kernel(const float* __restrict__ scores,
        u64* __restrict__ remw) {
    int w = blockIdx.x * 4 + (threadIdx.x >> 6);      // 128 waves over 32 blocks
    int lane = threadIdx.x & 63;
    u64 b = __ballot(scores[w * 64 + lane] > 0.0f);
    if (lane == 0) remw[w] = b;
}

// ---------------- kernel 7: single-wave greedy scan, LDS-staged row chunks ---------
// Per chunk: pop CCH speculative indices (pure VALU on fixed regs), issue CCH async
// global->LDS DMAs (one global_load_lds width=16 moves a whole 1KB row: 64 lanes x
// 16B), wait once, resolve all CCH from LDS (~120cy ds_read vs ~900cy HBM). The
// resolve phase re-pops the identical index sequence from a register snapshot of the
// spec set -- no index array, nothing spillable (round-5's arrays went to scratch:
// VGPR_Count=24).
__device__ __forceinline__ u64 bcast64(u64 v, int srclane) {
    u32 lo = (u32)__builtin_amdgcn_readlane((int)(u32)v, srclane);
    u32 hi = (u32)__builtin_amdgcn_readlane((int)(u32)(v >> 32), srclane);
    return ((u64)hi << 32) | lo;
}

__device__ __forceinline__ int ffidx(u64 w0, u64 w1) {
    u64 nz0 = __ballot(w0 != 0ull);
    if (nz0 != 0ull) {
        int w = __ffsll((unsigned long long)nz0) - 1;
        u64 word = bcast64(w0, w);
        return w * 64 + __ffsll((unsigned long long)word) - 1;
    }
    u64 nz1 = __ballot(w1 != 0ull);
    if (nz1 != 0ull) {
        int w = __ffsll((unsigned long long)nz1) - 1;
        u64 word = bcast64(w1, w);
        return (w + 64) * 64 + __ffsll((unsigned long long)word) - 1;
    }
    return -1;
}

__global__ __launch_bounds__(64) void nms_scan_kernel(const u64* __restrict__ mask,
        const u64* __restrict__ remw, const float* __restrict__ boxes,
        const float* __restrict__ scores, const float* __restrict__ classes,
        float* __restrict__ out) {
    __shared__ u64 rowbuf[CCH * 128];                 // 32 KB: CCH rows of 1 KB
    int lane = threadIdx.x;                           // exactly one wave
    u64 rem0 = remw[lane], rem1 = remw[64 + lane];
    // Speculation set: superset of rem in index order (popped bits removed,
    // suppression never applied) -> pops enumerate candidates in ascending index
    // (= descending score) order, exactly the greedy visit order.
    u64 sp0 = rem0, sp1 = rem1;
    int n = 0;
    bool done = false;
    while (!done && n < MAX_DET) {
        u64 sq0 = sp0, sq1 = sp1;                     // snapshot for resolve re-pop
        // phase 1: pop + issue async DMA per candidate (fire-and-forget on vmcnt)
        for (int c = 0; c < CCH; ++c) {
            int t = ffidx(sp0, sp1);
            if (t < 0) break;                         // wave-uniform
            int wt = t >> 6; u64 bt = 1ull << (t & 63);
            if (wt < 64) { if (lane == wt) sp0 &= ~bt; }
            else         { if (lane == wt - 64) sp1 &= ~bt; }
            const char* grow = (const char*)(mask + (size_t)t * 128) + lane * 16;
            __builtin_amdgcn_global_load_lds(
                (const __attribute__((address_space(1))) u32*)grow,
                (__attribute__((address_space(3))) u32*)&rowbuf[c * 128],
                16, 0, 0);
        }
        __builtin_amdgcn_s_waitcnt(0);                // drain DMA into LDS
        __asm__ volatile("" ::: "memory");            // no reorder of LDS reads above
        // phase 2: resolve from LDS, re-popping the same sequence from the snapshot
        for (int c = 0; c < CCH; ++c) {
            int t = ffidx(sq0, sq1);
            if (t < 0) { done = true; break; }
            int wt = t >> 6; u64 bt = 1ull << (t & 63);
            if (wt < 64) { if (lane == wt) sq0 &= ~bt; }
            else         { if (lane == wt - 64) sq1 &= ~bt; }
            u64 r0 = rowbuf[c * 128 + lane];
            u64 r1 = rowbuf[c * 128 + 64 + lane];
            bool mine = (wt < 64) ? ((lane == wt) && (rem0 & bt))
                                  : ((lane == wt - 64) && (rem1 & bt));
            if (__ballot(mine) != 0ull) {             // candidate still alive -> keep
                if (lane < 4) out[n * 4 + lane] = boxes[t * 4 + lane];
                if (lane == 0) { out[1200 + n] = classes[t]; out[1500 + n] = scores[t]; }
                ++n;
                rem0 &= ~r0; rem1 &= ~r1;
                if (wt < 64) { if (lane == wt) rem0 &= ~bt; }
                else         { if (lane == wt - 64) rem1 &= ~bt; }
                if (n >= MAX_DET) { done = true; break; }
            }
        }
    }
    // zero-fill the remaining slots (harness poisons d_out with 0xAA)
    for (int m = n; m < MAX_DET; ++m) {
        if (lane < 4) out[m * 4 + lane] = 0.0f;
        if (lane == 0) { out[1200 + m] = 0.0f; out[1500 + m] = 0.0f; }
    }
}

// ---------------- launch ----------------
extern "C" void kernel_launch(void* const* d_in, const int* in_sizes, int n_in,
                              void* d_out, int out_size, void* d_ws, size_t ws_size,
                              hipStream_t stream) {
    const float* preds = (const float*)d_in[0];
    char* ws = (char*)d_ws;

    // ws layout (bytes), total 9991104:
    //   [0, 262144)            sumhist     u32[65536]
    //   [262144, 262208)       meta        u32[16]   ([0]=counter, [1]=thresh)
    //   [262208, 263232)       remw        u64[128]
    //   [263232, 328768)       sorted      u64[8192]
    //   [328768, 1144768)      keys        u64[102000]
    //   [1144768, 1405888)     comp        u64[32640]
    //   [1405888, 1536960)     top_boxes   f32[8192*4]
    //   [1536960, 1569728)     top_scores  f32[8192]
    //   [1569728, 1602496)     top_classes f32[8192]
    //   [1602496, 9991104)     mask        u64[8192*128]  (8 MB; doubles as the
    //                                      32-plane histogram before mask_kernel)
    u32*   sumhist = (u32*)(ws + 0);
    u32*   meta    = (u32*)(ws + 262144);
    u64*   remw    = (u64*)(ws + 262208);
    u64*   sorted  = (u64*)(ws + 263232);
    u64*   keys    = (u64*)(ws + 328768);
    u64*   comp    = (u64*)(ws + 1144768);
    float* tboxes  = (float*)(ws + 1405888);
    float* tscores = (float*)(ws + 1536960);
    float* tclass  = (float*)(ws + 1569728);
    u64*   mask    = (u64*)(ws + 1602496);
    u32*   histP   = (u32*)(ws + 1602496);           // aliases mask region
    float* out     = (float*)d_out;

    hipMemsetAsync(ws, 0, 328768, stream);           // sumhist+meta+remw+sorted
    hipMemsetAsync(histP, 0, (size_t)NPLANE * 65536 * 4, stream);  // hist planes (8 MB)

    score_key_kernel<<<(NA + 3) / 4, 256, 0, stream>>>(preds, keys, histP);
    reduce_hist_kernel<<<256, 256, 0, stream>>>(histP, sumhist);
    cutoff_kernel<<<1, 1024, 0, stream>>>(sumhist, meta);
    compact_kernel<<<(NA + 255) / 256, 256, 0, stream>>>(keys, meta, comp);
    rank_kernel<<<(CAP + 255) / 256, 256, 0, stream>>>(comp, meta, sorted);
    gather_kernel<<<K_TOP / 4, 256, 0, stream>>>(sorted, preds, tboxes, tscores, tclass);
    mask_kernel<<<dim3(128, K_TOP / 256), 256, 0, stream>>>(tboxes, mask);
    valid_kernel<<<32, 256, 0, stream>>>(tscores, remw);
    nms_scan_kernel<<<1, 64, 0, stream>>>(mask, remw, tboxes, tscores, tclass, out);
}

// Round 7
// 367.350 us; speedup vs baseline: 1.9504x; 1.5765x over previous
//
#include <hip/hip_runtime.h>
#include <cstdint>

#define CONF_THRES 0.25f
#define IOU_THRES  0.45f
#define MAX_DET    300
#define K_TOP      8192
#define NA         102000
#define NCLS       80
#define ROWLEN     85
#define CAP        32640
#define NPLANE     32
#define WIN        512

typedef unsigned long long u64;
typedef unsigned int u32;

// ---------------- kernel 1: wave-per-anchor scores -> sortable keys + histogram ----
// Histogram goes to 32 replicated planes (plane = blockIdx&31, plane-major layout) to
// cut same-line L2 atomic serialization ~32x. Planes live in the mask region (free
// space: mask_kernel overwrites it only after cutoff consumed the histogram).
__global__ __launch_bounds__(256) void score_key_kernel(const float* __restrict__ preds,
        u64* __restrict__ keys, u32* __restrict__ histP) {
#pragma clang fp contract(off)
    int lane = threadIdx.x & 63;
    int i = blockIdx.x * 4 + (threadIdx.x >> 6);     // 4 waves/block, 1 anchor/wave
    if (i >= NA) return;
    const float* p = preds + (size_t)i * ROWLEN;
    float v0 = p[lane];                               // offsets 0..63
    float v1 = (lane < ROWLEN - 64) ? p[64 + lane] : 0.0f; // offsets 64..84
    float obj = __shfl(v0, 4);
    float m = (lane >= 5) ? v0 : 0.0f;                // classes 0..58 (scores >= 0)
    m = fmaxf(m, (lane < 21) ? v1 : 0.0f);            // classes 59..79
    for (int off = 32; off; off >>= 1) m = fmaxf(m, __shfl_xor(m, off));
    if (lane == 0) {
        float score = (obj > CONF_THRES) ? m * obj : 0.0f;
        u32 sb = __float_as_uint(score);              // score >= 0: order-preserving bits
        keys[i] = ((u64)sb << 32) | (u32)(~(u32)i);   // tie-break: smaller index wins
        if (sb != 0u)
            atomicAdd(&histP[((u32)blockIdx.x & (NPLANE - 1u)) * 65536u + (sb >> 16)], 1u);
    }
}

// ---------------- kernel 1b: fold 32 histogram planes -> sumhist ----------------
__global__ __launch_bounds__(256) void reduce_hist_kernel(const u32* __restrict__ histP,
        u32* __restrict__ sumhist) {
    int bin = blockIdx.x * 256 + threadIdx.x;         // grid 256 -> 65536 bins
    u32 s = 0;
#pragma unroll
    for (int r = 0; r < NPLANE; ++r) s += histP[r * 65536 + bin];
    sumhist[bin] = s;
}

// ---------------- kernel 2: find threshold bucket for top-K (parallel scan) --------
__global__ __launch_bounds__(1024) void cutoff_kernel(const u32* __restrict__ hist,
        u32* __restrict__ meta) {
    __shared__ u32 suf[1024];
    __shared__ int cbs;
    __shared__ u32 above_s;
    int t = threadIdx.x;
    u32 s = 0;
    const u32* hb = hist + t * 64;
    for (int b = 0; b < 64; ++b) s += hb[b];
    suf[t] = s;
    if (t == 0) { cbs = -1; above_s = 0; }
    __syncthreads();
    for (int off = 1; off < 1024; off <<= 1) {
        u32 add = (t + off < 1024) ? suf[t + off] : 0u;
        __syncthreads();
        suf[t] += add;
        __syncthreads();
    }
    u32 st = suf[t];
    u32 stn = (t < 1023) ? suf[t + 1] : 0u;
    if (st >= (u32)K_TOP && stn < (u32)K_TOP) {       // at most one thread
        cbs = t;
        above_s = stn;                                 // sum of chunks above cb
    }
    __syncthreads();
    int cb = cbs;
    if (t < 64) {                                      // wave 0 does the fine pass
        u32 thresh = 0;
        if (cb >= 0) {
            u32 above = above_s;
            u32 v = hist[cb * 64 + t];
            for (int off = 1; off < 64; off <<= 1) {
                u32 o = __shfl_down(v, off);
                if (t + off < 64) v += o;
            }
            u64 bal = __ballot(v + above >= (u32)K_TOP);
            int bstar = 63 - __builtin_clzll((unsigned long long)bal);
            thresh = ((u32)(cb * 64 + bstar)) << 16;
        }
        if (t == 0) meta[1] = thresh;                  // meta[0] zeroed by memset
    }
}

// ---------------- kernel 3: compact candidates above threshold ----------------
__global__ __launch_bounds__(256) void compact_kernel(const u64* __restrict__ keys,
        u32* __restrict__ meta, u64* __restrict__ comp) {
    __shared__ u32 woff[4];
    __shared__ u32 bbase;
    int i = blockIdx.x * 256 + threadIdx.x;
    int wid = threadIdx.x >> 6, lane = threadIdx.x & 63;
    u64 key = (i < NA) ? keys[i] : 0ull;
    u32 sb = (u32)(key >> 32);
    u32 th = meta[1];
    bool take = (i < NA) && (sb != 0u) && (sb >= th);
    u64 bal = __ballot(take);
    if (lane == 0) woff[wid] = (u32)__popcll(bal);
    __syncthreads();
    if (threadIdx.x == 0) {
        u32 t0 = woff[0], t1 = woff[1], t2 = woff[2], t3 = woff[3];
        bbase = atomicAdd(&meta[0], t0 + t1 + t2 + t3);
        woff[0] = 0; woff[1] = t0; woff[2] = t0 + t1; woff[3] = t0 + t1 + t2;
    }
    __syncthreads();
    if (take) {
        u32 pos = bbase + woff[wid] + (u32)__popcll(bal & ((1ull << lane) - 1ull));
        if (pos < CAP) comp[pos] = key;
    }
}

// ---------------- kernel 4: rank-by-counting -> sorted top-K keys ----------------
__global__ __launch_bounds__(256) void rank_kernel(const u64* __restrict__ comp,
        const u32* __restrict__ meta, u64* __restrict__ sorted) {
    __shared__ u64 tile[1024];
    u32 cnt = meta[0];
    int n = (int)(cnt < (u32)CAP ? cnt : (u32)CAP);
    if (blockIdx.x * 256 >= n) return;               // whole-block early exit (uniform)
    int tid = blockIdx.x * 256 + threadIdx.x;
    u64 key = (tid < n) ? comp[tid] : 0ull;
    u32 rank = 0;
    for (int base = 0; base < n; base += 1024) {
        int lim = (n - base < 1024) ? (n - base) : 1024;
        __syncthreads();
        for (int k = threadIdx.x; k < lim; k += 256) tile[k] = comp[base + k];
        __syncthreads();
        if (tid < n) {
            for (int j = 0; j < lim; ++j) rank += (tile[j] > key) ? 1u : 0u;
        }
    }
    if (tid < n && rank < (u32)K_TOP) sorted[rank] = key;  // keys unique -> perm
}

// ---------------- kernel 5: wave-per-anchor gather of boxes/classes/scores ---------
__global__ __launch_bounds__(256) void gather_kernel(const u64* __restrict__ sorted,
        const float* __restrict__ preds, float* __restrict__ boxes,
        float* __restrict__ scores, float* __restrict__ classes) {
#pragma clang fp contract(off)
    int lane = threadIdx.x & 63;
    int i = blockIdx.x * 4 + (threadIdx.x >> 6);     // i in [0, 8192)
    u64 key = sorted[i];
    u32 sb = (u32)(key >> 32);
    float score = __uint_as_float(sb);
    if (score > 0.0f) {                               // uniform across the wave
        u32 idx = ~(u32)(key & 0xffffffffull);
        const float* p = preds + (size_t)idx * ROWLEN;
        float v0 = p[lane];
        float v1 = (lane < ROWLEN - 64) ? p[64 + lane] : 0.0f;
        float obj = __shfl(v0, 4);
        u64 kb = 0;
        if (lane >= 5) {
            float q = v0 * obj;                       // class lane-5
            kb = ((u64)__float_as_uint(q) << 8) | (u32)(255 - (lane - 5));
        }
        if (lane < 21) {
            float q = v1 * obj;                       // class 59+lane
            u64 kb2 = ((u64)__float_as_uint(q) << 8) | (u32)(255 - (59 + lane));
            if (kb2 > kb) kb = kb2;
        }
        for (int off = 32; off; off >>= 1) {
            u64 o = __shfl_xor(kb, off);
            if (o > kb) kb = o;
        }
        u32 cls = 255u - (u32)(kb & 0xffull);
        float x = __shfl(v0, 0), y = __shfl(v0, 1);
        float w = __shfl(v0, 2), h = __shfl(v0, 3);
        if (lane == 0) {
            boxes[i * 4 + 0] = y - h * 0.5f;          // ymin
            boxes[i * 4 + 1] = x - w * 0.5f;          // xmin
            boxes[i * 4 + 2] = y + h * 0.5f;          // ymax
            boxes[i * 4 + 3] = x + w * 0.5f;          // xmax
            scores[i] = score;
            classes[i] = (float)cls;
        }
    } else if (lane == 0) {
        boxes[i * 4 + 0] = 0.0f; boxes[i * 4 + 1] = 0.0f;
        boxes[i * 4 + 2] = 0.0f; boxes[i * 4 + 3] = 0.0f;
        scores[i] = 0.0f;
        classes[i] = 0.0f;
    }
}

// ---------------- kernel 6: suppression bitmask (iou > thres, j > i) ----------------
__global__ __launch_bounds__(256) void mask_kernel(const float* __restrict__ boxes,
        u64* __restrict__ mask) {
#pragma clang fp contract(off)
    __shared__ float4 cb[64];
    int wj = blockIdx.x;                 // column word 0..127
    int i = blockIdx.y * 256 + threadIdx.x;
    int j0 = wj * 64;
    if (threadIdx.x < 64) cb[threadIdx.x] = ((const float4*)boxes)[j0 + threadIdx.x];
    __syncthreads();
    float4 bi = ((const float4*)boxes)[i];
    float area_i = (bi.z - bi.x) * (bi.w - bi.y);
    u64 bits = 0;
    if (j0 + 63 > i) {
        for (int k = 0; k < 64; ++k) {
            int j = j0 + k;
            if (j <= i) continue;
            float4 bj = cb[k];
            float area_j = (bj.z - bj.x) * (bj.w - bj.y);
            float ty = fmaxf(bi.x, bj.x);
            float tx = fmaxf(bi.y, bj.y);
            float by = fminf(bi.z, bj.z);
            float bx = fminf(bi.w, bj.w);
            float inter = fmaxf(by - ty, 0.0f) * fmaxf(bx - tx, 0.0f);
            float uni = (area_i + area_j) - inter;
            float iou = inter / (uni + 1e-9f);
            if (iou > IOU_THRES) bits |= (1ull << k);
        }
    }
    mask[(size_t)i * 128 + wj] = bits;
}

// ---------------- kernel 6b: validity words (rem init) for the scan ----------------
__global__ __launch_bounds__(256) void valid_kernel(const float* __restrict__ scores,
        u64* __restrict__ remw) {
    int w = blockIdx.x * 4 + (threadIdx.x >> 6);      // 128 waves over 32 blocks
    int lane = threadIdx.x & 63;
    u64 b = __ballot(scores[w * 64 + lane] > 0.0f);
    if (lane == 0) remw[w] = b;
}

// ---------------- kernel 7: single-wave greedy scan over an LDS-resident window ----
// The scan visits candidates in ascending index; with this data it finishes (300
// kept) well inside the first WIN=512 indices. Stage the 512x512 mask submatrix
// (32 KB) into LDS once, keep the 512-bit window-rem in lanes 0..7 (1 u64 each),
// and run the greedy chain entirely out of LDS: pop (ballot+ffs, ~50cy) ->
// ds_read_b64 row (~120cy) -> apply. Suppression is applied immediately, so every
// pop IS a keep -- no alive check, ~n iterations. Kept indices go to an LDS list;
// output is written afterwards by a fully parallel phase (no per-keep global
// round-trips in the serial loop). A never-hit-for-this-input fallback handles
// window exhaustion with n<300 (batch-apply kept rows to global rem, then the
// simple serial global scan).
__device__ __forceinline__ u64 bcast64(u64 v, int srclane) {
    u32 lo = (u32)__builtin_amdgcn_readlane((int)(u32)v, srclane);
    u32 hi = (u32)__builtin_amdgcn_readlane((int)(u32)(v >> 32), srclane);
    return ((u64)hi << 32) | lo;
}

__device__ __forceinline__ int ffidx8(u64 w) {       // first set bit over lanes 0..7
    u64 nz = __ballot(w != 0ull);
    if (nz == 0ull) return -1;
    int wd = __ffsll((unsigned long long)nz) - 1;
    u64 word = bcast64(w, wd);
    return wd * 64 + __ffsll((unsigned long long)word) - 1;
}

__device__ __forceinline__ int ffidx(u64 w0, u64 w1) {
    u64 nz0 = __ballot(w0 != 0ull);
    if (nz0 != 0ull) {
        int w = __ffsll((unsigned long long)nz0) - 1;
        u64 word = bcast64(w0, w);
        return w * 64 + __ffsll((unsigned long long)word) - 1;
    }
    u64 nz1 = __ballot(w1 != 0ull);
    if (nz1 != 0ull) {
        int w = __ffsll((unsigned long long)nz1) - 1;
        u64 word = bcast64(w1, w);
        return (w + 64) * 64 + __ffsll((unsigned long long)word) - 1;
    }
    return -1;
}

__global__ __launch_bounds__(64) void nms_scan_kernel(const u64* __restrict__ mask,
        const u64* __restrict__ remw, const float* __restrict__ boxes,
        const float* __restrict__ scores, const float* __restrict__ classes,
        float* __restrict__ out) {
    __shared__ u64 sub[WIN * 8];                      // 32 KB window submatrix
    __shared__ u32 ki[MAX_DET + 4];                   // kept indices
    int lane = threadIdx.x;                           // exactly one wave
    // stage sub[t*8+w] = mask[t*128+w], t<512, w<8 (16B per lane per iter)
#pragma unroll 4
    for (int t0 = 0; t0 < WIN; t0 += 16) {
        int t = t0 + (lane >> 2);
        int w = (lane & 3) * 2;
        uint4 v = *(const uint4*)&mask[(size_t)t * 128 + w];
        *(uint4*)&sub[t * 8 + w] = v;
    }
    u64 win = (lane < 8) ? remw[lane] : 0ull;         // window validity bits
    __syncthreads();
    int n = 0;
    while (n < MAX_DET) {
        int t = ffidx8(win);                          // next unsuppressed candidate
        if (t < 0) break;
        if (lane == 0) ki[n] = (u32)t;
        ++n;
        u64 row = (lane < 8) ? sub[t * 8 + lane] : 0ull;
        win &= ~row;                                  // suppress overlapped (j>t)
        if (lane == (t >> 6)) win &= ~(1ull << (t & 63));  // consume bit t
    }
    // ---- fallback: window exhausted with n < MAX_DET (not hit for bench input) ----
    if (n < MAX_DET) {
        u64 rem0 = (lane < 8) ? 0ull : remw[lane];    // window fully consumed
        u64 rem1 = remw[64 + lane];
        if ((__ballot(rem0 != 0ull) | __ballot(rem1 != 0ull)) != 0ull) {
            for (int m = 0; m < n; ++m) {             // batch-apply kept rows
                int k = (int)ki[m];
                rem0 &= ~mask[(size_t)k * 128 + lane];
                rem1 &= ~mask[(size_t)k * 128 + 64 + lane];
            }
            if (lane < 8) rem0 = 0ull;
            while (n < MAX_DET) {
                int i = ffidx(rem0, rem1);
                if (i < 0) break;
                if (lane == 0) ki[n] = (u32)i;
                ++n;
                const u64* row = mask + (size_t)i * 128;
                u64 r0 = row[lane], r1 = row[lane + 64];
                rem0 &= ~r0; rem1 &= ~r1;
                int wi = i >> 6;
                if (wi < 64) { if (lane == wi) rem0 &= ~(1ull << (i & 63)); }
                else         { if (lane == wi - 64) rem1 &= ~(1ull << (i & 63)); }
            }
        }
    }
    __syncthreads();
    // ---- parallel output phase: lane m handles detection m (5 strided rounds) ----
    for (int m = lane; m < MAX_DET; m += 64) {
        float4 b = make_float4(0.0f, 0.0f, 0.0f, 0.0f);
        float c = 0.0f, s = 0.0f;
        if (m < n) {
            int k = (int)ki[m];
            b = ((const float4*)boxes)[k];
            c = classes[k];
            s = scores[k];
        }
        ((float4*)out)[m] = b;
        out[1200 + m] = c;
        out[1500 + m] = s;
    }
}

// ---------------- launch ----------------
extern "C" void kernel_launch(void* const* d_in, const int* in_sizes, int n_in,
                              void* d_out, int out_size, void* d_ws, size_t ws_size,
                              hipStream_t stream) {
    const float* preds = (const float*)d_in[0];
    char* ws = (char*)d_ws;

    // ws layout (bytes), total 9991104:
    //   [0, 262144)            sumhist     u32[65536]
    //   [262144, 262208)       meta        u32[16]   ([0]=counter, [1]=thresh)
    //   [262208, 263232)       remw        u64[128]
    //   [263232, 328768)       sorted      u64[8192]
    //   [328768, 1144768)      keys        u64[102000]
    //   [1144768, 1405888)     comp        u64[32640]
    //   [1405888, 1536960)     top_boxes   f32[8192*4]
    //   [1536960, 1569728)     top_scores  f32[8192]
    //   [1569728, 1602496)     top_classes f32[8192]
    //   [1602496, 9991104)     mask        u64[8192*128]  (8 MB; doubles as the
    //                                      32-plane histogram before mask_kernel)
    u32*   sumhist = (u32*)(ws + 0);
    u32*   meta    = (u32*)(ws + 262144);
    u64*   remw    = (u64*)(ws + 262208);
    u64*   sorted  = (u64*)(ws + 263232);
    u64*   keys    = (u64*)(ws + 328768);
    u64*   comp    = (u64*)(ws + 1144768);
    float* tboxes  = (float*)(ws + 1405888);
    float* tscores = (float*)(ws + 1536960);
    float* tclass  = (float*)(ws + 1569728);
    u64*   mask    = (u64*)(ws + 1602496);
    u32*   histP   = (u32*)(ws + 1602496);           // aliases mask region
    float* out     = (float*)d_out;

    hipMemsetAsync(ws, 0, 328768, stream);           // sumhist+meta+remw+sorted
    hipMemsetAsync(histP, 0, (size_t)NPLANE * 65536 * 4, stream);  // hist planes (8 MB)

    score_key_kernel<<<(NA + 3) / 4, 256, 0, stream>>>(preds, keys, histP);
    reduce_hist_kernel<<<256, 256, 0, stream>>>(histP, sumhist);
    cutoff_kernel<<<1, 1024, 0, stream>>>(sumhist, meta);
    compact_kernel<<<(NA + 255) / 256, 256, 0, stream>>>(keys, meta, comp);
    rank_kernel<<<(CAP + 255) / 256, 256, 0, stream>>>(comp, meta, sorted);
    gather_kernel<<<K_TOP / 4, 256, 0, stream>>>(sorted, preds, tboxes, tscores, tclass);
    mask_kernel<<<dim3(128, K_TOP / 256), 256, 0, stream>>>(tboxes, mask);
    valid_kernel<<<32, 256, 0, stream>>>(tscores, remw);
    nms_scan_kernel<<<1, 64, 0, stream>>>(mask, remw, tboxes, tscores, tclass, out);
}

// Round 8
// 278.367 us; speedup vs baseline: 2.5739x; 1.3197x over previous
//
#include <hip/hip_runtime.h>
#include <cstdint>

#define CONF_THRES 0.25f
#define IOU_THRES  0.45f
#define MAX_DET    300
#define K_TOP      8192
#define NA         102000
#define NCLS       80
#define ROWLEN     85
#define CAP        32640
#define NPLANE     32
#define WIN        512

typedef unsigned long long u64;
typedef unsigned int u32;

// ---------------- kernel 1: wave-per-anchor scores -> sortable keys + histogram ----
__global__ __launch_bounds__(256) void score_key_kernel(const float* __restrict__ preds,
        u64* __restrict__ keys, u32* __restrict__ histP) {
#pragma clang fp contract(off)
    int lane = threadIdx.x & 63;
    int i = blockIdx.x * 4 + (threadIdx.x >> 6);     // 4 waves/block, 1 anchor/wave
    if (i >= NA) return;
    const float* p = preds + (size_t)i * ROWLEN;
    float v0 = p[lane];                               // offsets 0..63
    float v1 = (lane < ROWLEN - 64) ? p[64 + lane] : 0.0f; // offsets 64..84
    float obj = __shfl(v0, 4);
    float m = (lane >= 5) ? v0 : 0.0f;                // classes 0..58 (scores >= 0)
    m = fmaxf(m, (lane < 21) ? v1 : 0.0f);            // classes 59..79
    for (int off = 32; off; off >>= 1) m = fmaxf(m, __shfl_xor(m, off));
    if (lane == 0) {
        float score = (obj > CONF_THRES) ? m * obj : 0.0f;
        u32 sb = __float_as_uint(score);              // score >= 0: order-preserving bits
        keys[i] = ((u64)sb << 32) | (u32)(~(u32)i);   // tie-break: smaller index wins
        if (sb != 0u)
            atomicAdd(&histP[((u32)blockIdx.x & (NPLANE - 1u)) * 65536u + (sb >> 16)], 1u);
    }
}

// ---------------- kernel 1b: fold 32 histogram planes -> sumhist ----------------
__global__ __launch_bounds__(256) void reduce_hist_kernel(const u32* __restrict__ histP,
        u32* __restrict__ sumhist) {
    int bin = blockIdx.x * 256 + threadIdx.x;         // grid 256 -> 65536 bins
    u32 s = 0;
#pragma unroll
    for (int r = 0; r < NPLANE; ++r) s += histP[r * 65536 + bin];
    sumhist[bin] = s;
}

// ---------------- kernel 2: find threshold bucket for top-K (parallel scan) --------
__global__ __launch_bounds__(1024) void cutoff_kernel(const u32* __restrict__ hist,
        u32* __restrict__ meta) {
    __shared__ u32 suf[1024];
    __shared__ int cbs;
    __shared__ u32 above_s;
    int t = threadIdx.x;
    u32 s = 0;
    const u32* hb = hist + t * 64;
    for (int b = 0; b < 64; ++b) s += hb[b];
    suf[t] = s;
    if (t == 0) { cbs = -1; above_s = 0; }
    __syncthreads();
    for (int off = 1; off < 1024; off <<= 1) {
        u32 add = (t + off < 1024) ? suf[t + off] : 0u;
        __syncthreads();
        suf[t] += add;
        __syncthreads();
    }
    u32 st = suf[t];
    u32 stn = (t < 1023) ? suf[t + 1] : 0u;
    if (st >= (u32)K_TOP && stn < (u32)K_TOP) {       // at most one thread
        cbs = t;
        above_s = stn;                                 // sum of chunks above cb
    }
    __syncthreads();
    int cb = cbs;
    if (t < 64) {                                      // wave 0 does the fine pass
        u32 thresh = 0;
        if (cb >= 0) {
            u32 above = above_s;
            u32 v = hist[cb * 64 + t];
            for (int off = 1; off < 64; off <<= 1) {
                u32 o = __shfl_down(v, off);
                if (t + off < 64) v += o;
            }
            u64 bal = __ballot(v + above >= (u32)K_TOP);
            int bstar = 63 - __builtin_clzll((unsigned long long)bal);
            thresh = ((u32)(cb * 64 + bstar)) << 16;
        }
        if (t == 0) meta[1] = thresh;                  // meta[0] zeroed by memset
    }
}

// ---------------- kernel 3: compact candidates above threshold ----------------
__global__ __launch_bounds__(256) void compact_kernel(const u64* __restrict__ keys,
        u32* __restrict__ meta, u64* __restrict__ comp) {
    __shared__ u32 woff[4];
    __shared__ u32 bbase;
    int i = blockIdx.x * 256 + threadIdx.x;
    int wid = threadIdx.x >> 6, lane = threadIdx.x & 63;
    u64 key = (i < NA) ? keys[i] : 0ull;
    u32 sb = (u32)(key >> 32);
    u32 th = meta[1];
    bool take = (i < NA) && (sb != 0u) && (sb >= th);
    u64 bal = __ballot(take);
    if (lane == 0) woff[wid] = (u32)__popcll(bal);
    __syncthreads();
    if (threadIdx.x == 0) {
        u32 t0 = woff[0], t1 = woff[1], t2 = woff[2], t3 = woff[3];
        bbase = atomicAdd(&meta[0], t0 + t1 + t2 + t3);
        woff[0] = 0; woff[1] = t0; woff[2] = t0 + t1; woff[3] = t0 + t1 + t2;
    }
    __syncthreads();
    if (take) {
        u32 pos = bbase + woff[wid] + (u32)__popcll(bal & ((1ull << lane) - 1ull));
        if (pos < CAP) comp[pos] = key;
    }
}

// ---------------- kernel 4a: 2-D partial rank-by-counting ----------------
// Grid (128, 32): block (bx,by) ranks keys [bx*256, bx*256+256) against tile
// [by*1024, by*1024+1024). Tile is zero-padded -> fixed unrollable inner loop
// (0-key never outranks a real key). Partial ranks accumulate via atomicAdd
// (~306 active blocks x 256 adds over ~n distinct addresses: no contention).
// Replaces the serial-tiles rank_kernel: 121us at 1.5% occupancy (34 blocks on
// 256 CUs) -> full-machine spread.
__global__ __launch_bounds__(256) void rank_partial_kernel(const u64* __restrict__ comp,
        const u32* __restrict__ meta, u32* __restrict__ rankArr) {
    __shared__ u64 tile[1024];
    u32 cnt = meta[0];
    int n = (int)(cnt < (u32)CAP ? cnt : (u32)CAP);
    int i0 = blockIdx.x * 256;
    int j0 = blockIdx.y * 1024;
    if (i0 >= n || j0 >= n) return;                  // uniform early exit
    int lim = n - j0; if (lim > 1024) lim = 1024;
    for (int k = threadIdx.x; k < 1024; k += 256)
        tile[k] = (k < lim) ? comp[j0 + k] : 0ull;
    __syncthreads();
    int i = i0 + threadIdx.x;
    if (i < n) {
        u64 key = comp[i];
        u32 r = 0;
#pragma unroll 8
        for (int j = 0; j < 1024; ++j) r += (tile[j] > key) ? 1u : 0u;
        atomicAdd(&rankArr[i], r);
    }
}

// ---------------- kernel 4b: scatter keys to their rank ----------------
__global__ __launch_bounds__(256) void scatter_kernel(const u64* __restrict__ comp,
        const u32* __restrict__ meta, const u32* __restrict__ rankArr,
        u64* __restrict__ sorted) {
    u32 cnt = meta[0];
    int n = (int)(cnt < (u32)CAP ? cnt : (u32)CAP);
    int i = blockIdx.x * 256 + threadIdx.x;
    if (i < n) {
        u32 r = rankArr[i];
        if (r < (u32)K_TOP) sorted[r] = comp[i];     // keys unique -> permutation
    }
}

// ---------------- kernel 5: wave-per-anchor gather of boxes/classes/scores ---------
__global__ __launch_bounds__(256) void gather_kernel(const u64* __restrict__ sorted,
        const float* __restrict__ preds, float* __restrict__ boxes,
        float* __restrict__ scores, float* __restrict__ classes) {
#pragma clang fp contract(off)
    int lane = threadIdx.x & 63;
    int i = blockIdx.x * 4 + (threadIdx.x >> 6);     // i in [0, 8192)
    u64 key = sorted[i];
    u32 sb = (u32)(key >> 32);
    float score = __uint_as_float(sb);
    if (score > 0.0f) {                               // uniform across the wave
        u32 idx = ~(u32)(key & 0xffffffffull);
        const float* p = preds + (size_t)idx * ROWLEN;
        float v0 = p[lane];
        float v1 = (lane < ROWLEN - 64) ? p[64 + lane] : 0.0f;
        float obj = __shfl(v0, 4);
        u64 kb = 0;
        if (lane >= 5) {
            float q = v0 * obj;                       // class lane-5
            kb = ((u64)__float_as_uint(q) << 8) | (u32)(255 - (lane - 5));
        }
        if (lane < 21) {
            float q = v1 * obj;                       // class 59+lane
            u64 kb2 = ((u64)__float_as_uint(q) << 8) | (u32)(255 - (59 + lane));
            if (kb2 > kb) kb = kb2;
        }
        for (int off = 32; off; off >>= 1) {
            u64 o = __shfl_xor(kb, off);
            if (o > kb) kb = o;
        }
        u32 cls = 255u - (u32)(kb & 0xffull);
        float x = __shfl(v0, 0), y = __shfl(v0, 1);
        float w = __shfl(v0, 2), h = __shfl(v0, 3);
        if (lane == 0) {
            boxes[i * 4 + 0] = y - h * 0.5f;          // ymin
            boxes[i * 4 + 1] = x - w * 0.5f;          // xmin
            boxes[i * 4 + 2] = y + h * 0.5f;          // ymax
            boxes[i * 4 + 3] = x + w * 0.5f;          // xmax
            scores[i] = score;
            classes[i] = (float)cls;
        }
    } else if (lane == 0) {
        boxes[i * 4 + 0] = 0.0f; boxes[i * 4 + 1] = 0.0f;
        boxes[i * 4 + 2] = 0.0f; boxes[i * 4 + 3] = 0.0f;
        scores[i] = 0.0f;
        classes[i] = 0.0f;
    }
}

// ---------------- kernel 6: suppression bitmask (iou > thres, j > i) ----------------
__global__ __launch_bounds__(256) void mask_kernel(const float* __restrict__ boxes,
        u64* __restrict__ mask) {
#pragma clang fp contract(off)
    __shared__ float4 cb[64];
    int wj = blockIdx.x;                 // column word 0..127
    int i = blockIdx.y * 256 + threadIdx.x;
    int j0 = wj * 64;
    if (threadIdx.x < 64) cb[threadIdx.x] = ((const float4*)boxes)[j0 + threadIdx.x];
    __syncthreads();
    float4 bi = ((const float4*)boxes)[i];
    float area_i = (bi.z - bi.x) * (bi.w - bi.y);
    u64 bits = 0;
    if (j0 + 63 > i) {
        for (int k = 0; k < 64; ++k) {
            int j = j0 + k;
            if (j <= i) continue;
            float4 bj = cb[k];
            float area_j = (bj.z - bj.x) * (bj.w - bj.y);
            float ty = fmaxf(bi.x, bj.x);
            float tx = fmaxf(bi.y, bj.y);
            float by = fminf(bi.z, bj.z);
            float bx = fminf(bi.w, bj.w);
            float inter = fmaxf(by - ty, 0.0f) * fmaxf(bx - tx, 0.0f);
            float uni = (area_i + area_j) - inter;
            float iou = inter / (uni + 1e-9f);
            if (iou > IOU_THRES) bits |= (1ull << k);
        }
    }
    mask[(size_t)i * 128 + wj] = bits;
}

// ---------------- kernel 6b: validity words (rem init) for the scan ----------------
__global__ __launch_bounds__(256) void valid_kernel(const float* __restrict__ scores,
        u64* __restrict__ remw) {
    int w = blockIdx.x * 4 + (threadIdx.x >> 6);      // 128 waves over 32 blocks
    int lane = threadIdx.x & 63;
    u64 b = __ballot(scores[w * 64 + lane] > 0.0f);
    if (lane == 0) remw[w] = b;
}

// ---------------- kernel 7: single-wave greedy scan over an LDS-resident window ----
__device__ __forceinline__ u64 bcast64(u64 v, int srclane) {
    u32 lo = (u32)__builtin_amdgcn_readlane((int)(u32)v, srclane);
    u32 hi = (u32)__builtin_amdgcn_readlane((int)(u32)(v >> 32), srclane);
    return ((u64)hi << 32) | lo;
}

__device__ __forceinline__ int ffidx8(u64 w) {       // first set bit over lanes 0..7
    u64 nz = __ballot(w != 0ull);
    if (nz == 0ull) return -1;
    int wd = __ffsll((unsigned long long)nz) - 1;
    u64 word = bcast64(w, wd);
    return wd * 64 + __ffsll((unsigned long long)word) - 1;
}

__device__ __forceinline__ int ffidx(u64 w0, u64 w1) {
    u64 nz0 = __ballot(w0 != 0ull);
    if (nz0 != 0ull) {
        int w = __ffsll((unsigned long long)nz0) - 1;
        u64 word = bcast64(w0, w);
        return w * 64 + __ffsll((unsigned long long)word) - 1;
    }
    u64 nz1 = __ballot(w1 != 0ull);
    if (nz1 != 0ull) {
        int w = __ffsll((unsigned long long)nz1) - 1;
        u64 word = bcast64(w1, w);
        return (w + 64) * 64 + __ffsll((unsigned long long)word) - 1;
    }
    return -1;
}

__global__ __launch_bounds__(64) void nms_scan_kernel(const u64* __restrict__ mask,
        const u64* __restrict__ remw, const float* __restrict__ boxes,
        const float* __restrict__ scores, const float* __restrict__ classes,
        float* __restrict__ out) {
    __shared__ u64 sub[WIN * 8];                      // 32 KB window submatrix
    __shared__ u32 ki[MAX_DET + 4];                   // kept indices
    int lane = threadIdx.x;                           // exactly one wave
#pragma unroll 4
    for (int t0 = 0; t0 < WIN; t0 += 16) {
        int t = t0 + (lane >> 2);
        int w = (lane & 3) * 2;
        uint4 v = *(const uint4*)&mask[(size_t)t * 128 + w];
        *(uint4*)&sub[t * 8 + w] = v;
    }
    u64 win = (lane < 8) ? remw[lane] : 0ull;         // window validity bits
    __syncthreads();
    int n = 0;
    while (n < MAX_DET) {
        int t = ffidx8(win);                          // next unsuppressed candidate
        if (t < 0) break;
        if (lane == 0) ki[n] = (u32)t;
        ++n;
        u64 row = (lane < 8) ? sub[t * 8 + lane] : 0ull;
        win &= ~row;                                  // suppress overlapped (j>t)
        if (lane == (t >> 6)) win &= ~(1ull << (t & 63));  // consume bit t
    }
    // ---- fallback: window exhausted with n < MAX_DET (not hit for bench input) ----
    if (n < MAX_DET) {
        u64 rem0 = (lane < 8) ? 0ull : remw[lane];    // window fully consumed
        u64 rem1 = remw[64 + lane];
        if ((__ballot(rem0 != 0ull) | __ballot(rem1 != 0ull)) != 0ull) {
            for (int m = 0; m < n; ++m) {             // batch-apply kept rows
                int k = (int)ki[m];
                rem0 &= ~mask[(size_t)k * 128 + lane];
                rem1 &= ~mask[(size_t)k * 128 + 64 + lane];
            }
            if (lane < 8) rem0 = 0ull;
            while (n < MAX_DET) {
                int i = ffidx(rem0, rem1);
                if (i < 0) break;
                if (lane == 0) ki[n] = (u32)i;
                ++n;
                const u64* row = mask + (size_t)i * 128;
                u64 r0 = row[lane], r1 = row[lane + 64];
                rem0 &= ~r0; rem1 &= ~r1;
                int wi = i >> 6;
                if (wi < 64) { if (lane == wi) rem0 &= ~(1ull << (i & 63)); }
                else         { if (lane == wi - 64) rem1 &= ~(1ull << (i & 63)); }
            }
        }
    }
    __syncthreads();
    // ---- parallel output phase: lane m handles detection m (5 strided rounds) ----
    for (int m = lane; m < MAX_DET; m += 64) {
        float4 b = make_float4(0.0f, 0.0f, 0.0f, 0.0f);
        float c = 0.0f, s = 0.0f;
        if (m < n) {
            int k = (int)ki[m];
            b = ((const float4*)boxes)[k];
            c = classes[k];
            s = scores[k];
        }
        ((float4*)out)[m] = b;
        out[1200 + m] = c;
        out[1500 + m] = s;
    }
}

// ---------------- launch ----------------
extern "C" void kernel_launch(void* const* d_in, const int* in_sizes, int n_in,
                              void* d_out, int out_size, void* d_ws, size_t ws_size,
                              hipStream_t stream) {
    const float* preds = (const float*)d_in[0];
    char* ws = (char*)d_ws;

    // ws layout (bytes), total 9991104:
    //   [0, 262144)            sumhist     u32[65536]
    //   [262144, 262208)       meta        u32[16]   ([0]=counter, [1]=thresh)
    //   [262208, 263232)       remw        u64[128]
    //   [263232, 328768)       sorted      u64[8192]
    //   [328768, 1144768)      keys        u64[102000] (dead after compact;
    //                                      front 130560 B reused as rankArr)
    //   [1144768, 1405888)     comp        u64[32640]
    //   [1405888, 1536960)     top_boxes   f32[8192*4]
    //   [1536960, 1569728)     top_scores  f32[8192]
    //   [1569728, 1602496)     top_classes f32[8192]
    //   [1602496, 9991104)     mask        u64[8192*128]  (8 MB; doubles as the
    //                                      32-plane histogram before mask_kernel)
    u32*   sumhist = (u32*)(ws + 0);
    u32*   meta    = (u32*)(ws + 262144);
    u64*   remw    = (u64*)(ws + 262208);
    u64*   sorted  = (u64*)(ws + 263232);
    u64*   keys    = (u64*)(ws + 328768);
    u32*   rankArr = (u32*)(ws + 328768);            // aliases keys (dead by then)
    u64*   comp    = (u64*)(ws + 1144768);
    float* tboxes  = (float*)(ws + 1405888);
    float* tscores = (float*)(ws + 1536960);
    float* tclass  = (float*)(ws + 1569728);
    u64*   mask    = (u64*)(ws + 1602496);
    u32*   histP   = (u32*)(ws + 1602496);           // aliases mask region
    float* out     = (float*)d_out;

    hipMemsetAsync(ws, 0, 328768, stream);           // sumhist+meta+remw+sorted
    hipMemsetAsync(histP, 0, (size_t)NPLANE * 65536 * 4, stream);  // hist planes (8 MB)

    score_key_kernel<<<(NA + 3) / 4, 256, 0, stream>>>(preds, keys, histP);
    reduce_hist_kernel<<<256, 256, 0, stream>>>(histP, sumhist);
    cutoff_kernel<<<1, 1024, 0, stream>>>(sumhist, meta);
    compact_kernel<<<(NA + 255) / 256, 256, 0, stream>>>(keys, meta, comp);
    hipMemsetAsync(rankArr, 0, (size_t)CAP * 4, stream);   // keys dead: zero rankArr
    rank_partial_kernel<<<dim3((CAP + 255) / 256, (CAP + 1023) / 1024), 256, 0, stream>>>(
            comp, meta, rankArr);
    scatter_kernel<<<(CAP + 255) / 256, 256, 0, stream>>>(comp, meta, rankArr, sorted);
    gather_kernel<<<K_TOP / 4, 256, 0, stream>>>(sorted, preds, tboxes, tscores, tclass);
    mask_kernel<<<dim3(128, K_TOP / 256), 256, 0, stream>>>(tboxes, mask);
    valid_kernel<<<32, 256, 0, stream>>>(tscores, remw);
    nms_scan_kernel<<<1, 64, 0, stream>>>(mask, remw, tboxes, tscores, tclass, out);
}

// Round 9
// 266.443 us; speedup vs baseline: 2.6891x; 1.0448x over previous
//
#include <hip/hip_runtime.h>
#include <cstdint>

#define CONF_THRES 0.25f
#define IOU_THRES  0.45f
#define MAX_DET    300
#define K_TOP      8192
#define NA         102000
#define NCLS       80
#define ROWLEN     85
#define CAP        32640
#define NPLANE     32
#define WIN        512
#define SSTR       9            // LDS row stride in u64 (pad 8->9: bank spread)

typedef unsigned long long u64;
typedef unsigned int u32;

// ---------------- kernel 1: wave-per-anchor scores -> sortable keys + histogram ----
__global__ __launch_bounds__(256) void score_key_kernel(const float* __restrict__ preds,
        u64* __restrict__ keys, u32* __restrict__ histP) {
#pragma clang fp contract(off)
    int lane = threadIdx.x & 63;
    int i = blockIdx.x * 4 + (threadIdx.x >> 6);     // 4 waves/block, 1 anchor/wave
    if (i >= NA) return;
    const float* p = preds + (size_t)i * ROWLEN;
    float v0 = p[lane];                               // offsets 0..63
    float v1 = (lane < ROWLEN - 64) ? p[64 + lane] : 0.0f; // offsets 64..84
    float obj = __shfl(v0, 4);
    float m = (lane >= 5) ? v0 : 0.0f;                // classes 0..58 (scores >= 0)
    m = fmaxf(m, (lane < 21) ? v1 : 0.0f);            // classes 59..79
    for (int off = 32; off; off >>= 1) m = fmaxf(m, __shfl_xor(m, off));
    if (lane == 0) {
        float score = (obj > CONF_THRES) ? m * obj : 0.0f;
        u32 sb = __float_as_uint(score);              // score >= 0: order-preserving bits
        keys[i] = ((u64)sb << 32) | (u32)(~(u32)i);   // tie-break: smaller index wins
        if (sb != 0u)
            atomicAdd(&histP[((u32)blockIdx.x & (NPLANE - 1u)) * 65536u + (sb >> 16)], 1u);
    }
}

// ---------------- kernel 1b: fold 32 histogram planes -> sumhist ----------------
__global__ __launch_bounds__(256) void reduce_hist_kernel(const u32* __restrict__ histP,
        u32* __restrict__ sumhist) {
    int bin = blockIdx.x * 256 + threadIdx.x;         // grid 256 -> 65536 bins
    u32 s = 0;
#pragma unroll
    for (int r = 0; r < NPLANE; ++r) s += histP[r * 65536 + bin];
    sumhist[bin] = s;
}

// ---------------- kernel 2: find threshold bucket for top-K (parallel scan) --------
__global__ __launch_bounds__(1024) void cutoff_kernel(const u32* __restrict__ hist,
        u32* __restrict__ meta) {
    __shared__ u32 suf[1024];
    __shared__ int cbs;
    __shared__ u32 above_s;
    int t = threadIdx.x;
    u32 s = 0;
    const u32* hb = hist + t * 64;
    for (int b = 0; b < 64; ++b) s += hb[b];
    suf[t] = s;
    if (t == 0) { cbs = -1; above_s = 0; }
    __syncthreads();
    for (int off = 1; off < 1024; off <<= 1) {
        u32 add = (t + off < 1024) ? suf[t + off] : 0u;
        __syncthreads();
        suf[t] += add;
        __syncthreads();
    }
    u32 st = suf[t];
    u32 stn = (t < 1023) ? suf[t + 1] : 0u;
    if (st >= (u32)K_TOP && stn < (u32)K_TOP) {       // at most one thread
        cbs = t;
        above_s = stn;                                 // sum of chunks above cb
    }
    __syncthreads();
    int cb = cbs;
    if (t < 64) {                                      // wave 0 does the fine pass
        u32 thresh = 0;
        if (cb >= 0) {
            u32 above = above_s;
            u32 v = hist[cb * 64 + t];
            for (int off = 1; off < 64; off <<= 1) {
                u32 o = __shfl_down(v, off);
                if (t + off < 64) v += o;
            }
            u64 bal = __ballot(v + above >= (u32)K_TOP);
            int bstar = 63 - __builtin_clzll((unsigned long long)bal);
            thresh = ((u32)(cb * 64 + bstar)) << 16;
        }
        if (t == 0) meta[1] = thresh;                  // meta[0] zeroed by memset
    }
}

// ---------------- kernel 3: compact candidates above threshold ----------------
__global__ __launch_bounds__(256) void compact_kernel(const u64* __restrict__ keys,
        u32* __restrict__ meta, u64* __restrict__ comp) {
    __shared__ u32 woff[4];
    __shared__ u32 bbase;
    int i = blockIdx.x * 256 + threadIdx.x;
    int wid = threadIdx.x >> 6, lane = threadIdx.x & 63;
    u64 key = (i < NA) ? keys[i] : 0ull;
    u32 sb = (u32)(key >> 32);
    u32 th = meta[1];
    bool take = (i < NA) && (sb != 0u) && (sb >= th);
    u64 bal = __ballot(take);
    if (lane == 0) woff[wid] = (u32)__popcll(bal);
    __syncthreads();
    if (threadIdx.x == 0) {
        u32 t0 = woff[0], t1 = woff[1], t2 = woff[2], t3 = woff[3];
        bbase = atomicAdd(&meta[0], t0 + t1 + t2 + t3);
        woff[0] = 0; woff[1] = t0; woff[2] = t0 + t1; woff[3] = t0 + t1 + t2;
    }
    __syncthreads();
    if (take) {
        u32 pos = bbase + woff[wid] + (u32)__popcll(bal & ((1ull << lane) - 1ull));
        if (pos < CAP) comp[pos] = key;
    }
}

// ---------------- kernel 4a: 2-D partial rank-by-counting ----------------
__global__ __launch_bounds__(256) void rank_partial_kernel(const u64* __restrict__ comp,
        const u32* __restrict__ meta, u32* __restrict__ rankArr) {
    __shared__ u64 tile[1024];
    u32 cnt = meta[0];
    int n = (int)(cnt < (u32)CAP ? cnt : (u32)CAP);
    int i0 = blockIdx.x * 256;
    int j0 = blockIdx.y * 1024;
    if (i0 >= n || j0 >= n) return;                  // uniform early exit
    int lim = n - j0; if (lim > 1024) lim = 1024;
    for (int k = threadIdx.x; k < 1024; k += 256)
        tile[k] = (k < lim) ? comp[j0 + k] : 0ull;
    __syncthreads();
    int i = i0 + threadIdx.x;
    if (i < n) {
        u64 key = comp[i];
        u32 r = 0;
#pragma unroll 8
        for (int j = 0; j < 1024; ++j) r += (tile[j] > key) ? 1u : 0u;
        atomicAdd(&rankArr[i], r);
    }
}

// ---------------- kernel 4b: scatter keys to their rank ----------------
__global__ __launch_bounds__(256) void scatter_kernel(const u64* __restrict__ comp,
        const u32* __restrict__ meta, const u32* __restrict__ rankArr,
        u64* __restrict__ sorted) {
    u32 cnt = meta[0];
    int n = (int)(cnt < (u32)CAP ? cnt : (u32)CAP);
    int i = blockIdx.x * 256 + threadIdx.x;
    if (i < n) {
        u32 r = rankArr[i];
        if (r < (u32)K_TOP) sorted[r] = comp[i];     // keys unique -> permutation
    }
}

// ---------------- kernel 5: wave-per-anchor gather of boxes/classes/scores ---------
__global__ __launch_bounds__(256) void gather_kernel(const u64* __restrict__ sorted,
        const float* __restrict__ preds, float* __restrict__ boxes,
        float* __restrict__ scores, float* __restrict__ classes) {
#pragma clang fp contract(off)
    int lane = threadIdx.x & 63;
    int i = blockIdx.x * 4 + (threadIdx.x >> 6);     // i in [0, 8192)
    u64 key = sorted[i];
    u32 sb = (u32)(key >> 32);
    float score = __uint_as_float(sb);
    if (score > 0.0f) {                               // uniform across the wave
        u32 idx = ~(u32)(key & 0xffffffffull);
        const float* p = preds + (size_t)idx * ROWLEN;
        float v0 = p[lane];
        float v1 = (lane < ROWLEN - 64) ? p[64 + lane] : 0.0f;
        float obj = __shfl(v0, 4);
        u64 kb = 0;
        if (lane >= 5) {
            float q = v0 * obj;                       // class lane-5
            kb = ((u64)__float_as_uint(q) << 8) | (u32)(255 - (lane - 5));
        }
        if (lane < 21) {
            float q = v1 * obj;                       // class 59+lane
            u64 kb2 = ((u64)__float_as_uint(q) << 8) | (u32)(255 - (59 + lane));
            if (kb2 > kb) kb = kb2;
        }
        for (int off = 32; off; off >>= 1) {
            u64 o = __shfl_xor(kb, off);
            if (o > kb) kb = o;
        }
        u32 cls = 255u - (u32)(kb & 0xffull);
        float x = __shfl(v0, 0), y = __shfl(v0, 1);
        float w = __shfl(v0, 2), h = __shfl(v0, 3);
        if (lane == 0) {
            boxes[i * 4 + 0] = y - h * 0.5f;          // ymin
            boxes[i * 4 + 1] = x - w * 0.5f;          // xmin
            boxes[i * 4 + 2] = y + h * 0.5f;          // ymax
            boxes[i * 4 + 3] = x + w * 0.5f;          // xmax
            scores[i] = score;
            classes[i] = (float)cls;
        }
    } else if (lane == 0) {
        boxes[i * 4 + 0] = 0.0f; boxes[i * 4 + 1] = 0.0f;
        boxes[i * 4 + 2] = 0.0f; boxes[i * 4 + 3] = 0.0f;
        scores[i] = 0.0f;
        classes[i] = 0.0f;
    }
}

// ---------------- kernel 6: suppression bitmask (iou > thres, j > i) ----------------
__global__ __launch_bounds__(256) void mask_kernel(const float* __restrict__ boxes,
        u64* __restrict__ mask) {
#pragma clang fp contract(off)
    __shared__ float4 cb[64];
    int wj = blockIdx.x;                 // column word 0..127
    int i = blockIdx.y * 256 + threadIdx.x;
    int j0 = wj * 64;
    if (threadIdx.x < 64) cb[threadIdx.x] = ((const float4*)boxes)[j0 + threadIdx.x];
    __syncthreads();
    float4 bi = ((const float4*)boxes)[i];
    float area_i = (bi.z - bi.x) * (bi.w - bi.y);
    u64 bits = 0;
    if (j0 + 63 > i) {
        for (int k = 0; k < 64; ++k) {
            int j = j0 + k;
            if (j <= i) continue;
            float4 bj = cb[k];
            float area_j = (bj.z - bj.x) * (bj.w - bj.y);
            float ty = fmaxf(bi.x, bj.x);
            float tx = fmaxf(bi.y, bj.y);
            float by = fminf(bi.z, bj.z);
            float bx = fminf(bi.w, bj.w);
            float inter = fmaxf(by - ty, 0.0f) * fmaxf(bx - tx, 0.0f);
            float uni = (area_i + area_j) - inter;
            float iou = inter / (uni + 1e-9f);
            if (iou > IOU_THRES) bits |= (1ull << k);
        }
    }
    mask[(size_t)i * 128 + wj] = bits;
}

// ---------------- kernel 6b: validity words (rem init) for the scan ----------------
__global__ __launch_bounds__(256) void valid_kernel(const float* __restrict__ scores,
        u64* __restrict__ remw) {
    int w = blockIdx.x * 4 + (threadIdx.x >> 6);      // 128 waves over 32 blocks
    int lane = threadIdx.x & 63;
    u64 b = __ballot(scores[w * 64 + lane] > 0.0f);
    if (lane == 0) remw[w] = b;
}

// ---------------- kernel 7: single-wave greedy scan, register-resident chain -------
// Window state = 8 wave-uniform u64 registers (replicated per lane); within-word
// suppression slices come from the preloaded diagonal 64x64 blocks via v_readlane
// (~10cy) -- the per-keep serial chain is register-only (~40cy vs round-8's ~760cy
// ballot->ds_read->apply chain). Cross-word suppression applied once per word,
// data-parallel: lane l reads kept-row (w*64+l)'s later words (independent
// ds_reads), 6-step shfl_xor OR-butterfly folds all keeps at once. ki list
// reconstructed in parallel from kept bitmaps afterwards.
__device__ __forceinline__ u64 bcast64(u64 v, int srclane) {
    u32 lo = (u32)__builtin_amdgcn_readlane((int)(u32)v, srclane);
    u32 hi = (u32)__builtin_amdgcn_readlane((int)(u32)(v >> 32), srclane);
    return ((u64)hi << 32) | lo;
}

__device__ __forceinline__ u64 shfl_xor64(u64 v, int m) {
    u32 lo = __shfl_xor((u32)v, m, 64);
    u32 hi = __shfl_xor((u32)(v >> 32), m, 64);
    return ((u64)hi << 32) | lo;
}

__device__ __forceinline__ int ffidx(u64 w0, u64 w1) {
    u64 nz0 = __ballot(w0 != 0ull);
    if (nz0 != 0ull) {
        int w = __ffsll((unsigned long long)nz0) - 1;
        u64 word = bcast64(w0, w);
        return w * 64 + __ffsll((unsigned long long)word) - 1;
    }
    u64 nz1 = __ballot(w1 != 0ull);
    if (nz1 != 0ull) {
        int w = __ffsll((unsigned long long)nz1) - 1;
        u64 word = bcast64(w1, w);
        return (w + 64) * 64 + __ffsll((unsigned long long)word) - 1;
    }
    return -1;
}

__global__ __launch_bounds__(64) void nms_scan_kernel(const u64* __restrict__ mask,
        const u64* __restrict__ remw, const float* __restrict__ boxes,
        const float* __restrict__ scores, const float* __restrict__ classes,
        float* __restrict__ out) {
    __shared__ u64 sub[WIN * SSTR];                   // 36 KB padded window submatrix
    __shared__ u32 ki[MAX_DET + 4];                   // kept indices
    int lane = threadIdx.x;                           // exactly one wave
    // stage sub[t*SSTR+w] = mask[t*128+w], t<512, w<8
#pragma unroll 4
    for (int t0 = 0; t0 < WIN; t0 += 16) {
        int t = t0 + (lane >> 2);
        int w = (lane & 3) * 2;
        uint4 v = *(const uint4*)&mask[(size_t)t * 128 + w];
        sub[t * SSTR + w]     = ((u64)v.y << 32) | v.x;
        sub[t * SSTR + w + 1] = ((u64)v.w << 32) | v.z;
    }
    __syncthreads();
    // diagonal blocks: lane l holds row (w*64+l)'s own-word slice
    u64 diag[8];
#pragma unroll
    for (int w = 0; w < 8; ++w) diag[w] = sub[(w * 64 + lane) * SSTR + w];
    // window remaining-set, replicated wave-uniform (8 u64 regs per lane)
    u64 rem[8];
#pragma unroll
    for (int w = 0; w < 8; ++w) rem[w] = remw[w];
    u64 keptW[8];
    int n = 0;
#pragma unroll
    for (int w = 0; w < 8; ++w) {
        u64 kw = 0;
        if (n < MAX_DET) {
            u64 cur = rem[w];
            // serial pops: register-only chain (~40cy/keep)
            while (__ballot(cur != 0ull) != 0ull && n < MAX_DET) {
                int bv = __ffsll((unsigned long long)cur) - 1;
                int b = __builtin_amdgcn_readfirstlane(bv);
                u64 slice = bcast64(diag[w], b);      // row (w*64+b), word w
                kw |= (1ull << b);
                cur &= ~slice;
                cur &= ~(1ull << b);
                ++n;
            }
            // parallel cross-word apply: lane l reads kept-row w*64+l's later words
            if (w < 7) {
                bool has = ((kw >> lane) & 1ull) != 0ull;
                int t = w * 64 + lane;
                u64 rr[8];
#pragma unroll
                for (int w2 = 0; w2 < 8; ++w2)
                    rr[w2] = (w2 > w && has) ? sub[t * SSTR + w2] : 0ull;
#pragma unroll
                for (int w2 = 0; w2 < 8; ++w2) {
                    if (w2 > w) {
                        u64 v = rr[w2];
                        for (int off = 32; off; off >>= 1) v |= shfl_xor64(v, off);
                        rem[w2] &= ~v;                // uniform after butterfly
                    }
                }
            }
        }
        keptW[w] = kw;
    }
    // reconstruct kept-index list in LDS (parallel; ascending order = greedy order)
    int base = 0;
#pragma unroll
    for (int w = 0; w < 8; ++w) {
        u64 kw = keptW[w];
        if ((kw >> lane) & 1ull) {
            int r = (int)__popcll(kw & ((1ull << lane) - 1ull));
            ki[base + r] = (u32)(w * 64 + lane);
        }
        base += (int)__popcll(kw);
    }
    __syncthreads();
    // ---- fallback: window exhausted with n < MAX_DET (not hit for bench input) ----
    if (n < MAX_DET) {
        u64 rem0 = (lane < 8) ? 0ull : remw[lane];    // window fully consumed
        u64 rem1 = remw[64 + lane];
        if ((__ballot(rem0 != 0ull) | __ballot(rem1 != 0ull)) != 0ull) {
            for (int m = 0; m < n; ++m) {             // batch-apply kept rows
                int k = (int)ki[m];
                rem0 &= ~mask[(size_t)k * 128 + lane];
                rem1 &= ~mask[(size_t)k * 128 + 64 + lane];
            }
            if (lane < 8) rem0 = 0ull;
            while (n < MAX_DET) {
                int i = ffidx(rem0, rem1);
                if (i < 0) break;
                if (lane == 0) ki[n] = (u32)i;
                ++n;
                const u64* row = mask + (size_t)i * 128;
                u64 r0 = row[lane], r1 = row[lane + 64];
                rem0 &= ~r0; rem1 &= ~r1;
                int wi = i >> 6;
                if (wi < 64) { if (lane == wi) rem0 &= ~(1ull << (i & 63)); }
                else         { if (lane == wi - 64) rem1 &= ~(1ull << (i & 63)); }
            }
            __syncthreads();
        }
    }
    // ---- parallel output phase: lane m handles detection m (5 strided rounds) ----
    for (int m = lane; m < MAX_DET; m += 64) {
        float4 b = make_float4(0.0f, 0.0f, 0.0f, 0.0f);
        float c = 0.0f, s = 0.0f;
        if (m < n) {
            int k = (int)ki[m];
            b = ((const float4*)boxes)[k];
            c = classes[k];
            s = scores[k];
        }
        ((float4*)out)[m] = b;
        out[1200 + m] = c;
        out[1500 + m] = s;
    }
}

// ---------------- launch ----------------
extern "C" void kernel_launch(void* const* d_in, const int* in_sizes, int n_in,
                              void* d_out, int out_size, void* d_ws, size_t ws_size,
                              hipStream_t stream) {
    const float* preds = (const float*)d_in[0];
    char* ws = (char*)d_ws;

    // ws layout (bytes), total 9991104:
    //   [0, 262144)            sumhist     u32[65536]
    //   [262144, 262208)       meta        u32[16]   ([0]=counter, [1]=thresh)
    //   [262208, 263232)       remw        u64[128]
    //   [263232, 328768)       sorted      u64[8192]
    //   [328768, 1144768)      keys        u64[102000] (dead after compact;
    //                                      front 130560 B reused as rankArr)
    //   [1144768, 1405888)     comp        u64[32640]
    //   [1405888, 1536960)     top_boxes   f32[8192*4]
    //   [1536960, 1569728)     top_scores  f32[8192]
    //   [1569728, 1602496)     top_classes f32[8192]
    //   [1602496, 9991104)     mask        u64[8192*128]  (8 MB; doubles as the
    //                                      32-plane histogram before mask_kernel)
    u32*   sumhist = (u32*)(ws + 0);
    u32*   meta    = (u32*)(ws + 262144);
    u64*   remw    = (u64*)(ws + 262208);
    u64*   sorted  = (u64*)(ws + 263232);
    u64*   keys    = (u64*)(ws + 328768);
    u32*   rankArr = (u32*)(ws + 328768);            // aliases keys (dead by then)
    u64*   comp    = (u64*)(ws + 1144768);
    float* tboxes  = (float*)(ws + 1405888);
    float* tscores = (float*)(ws + 1536960);
    float* tclass  = (float*)(ws + 1569728);
    u64*   mask    = (u64*)(ws + 1602496);
    u32*   histP   = (u32*)(ws + 1602496);           // aliases mask region
    float* out     = (float*)d_out;

    hipMemsetAsync(ws, 0, 328768, stream);           // sumhist+meta+remw+sorted
    hipMemsetAsync(histP, 0, (size_t)NPLANE * 65536 * 4, stream);  // hist planes (8 MB)

    score_key_kernel<<<(NA + 3) / 4, 256, 0, stream>>>(preds, keys, histP);
    reduce_hist_kernel<<<256, 256, 0, stream>>>(histP, sumhist);
    cutoff_kernel<<<1, 1024, 0, stream>>>(sumhist, meta);
    compact_kernel<<<(NA + 255) / 256, 256, 0, stream>>>(keys, meta, comp);
    hipMemsetAsync(rankArr, 0, (size_t)CAP * 4, stream);   // keys dead: zero rankArr
    rank_partial_kernel<<<dim3((CAP + 255) / 256, (CAP + 1023) / 1024), 256, 0, stream>>>(
            comp, meta, rankArr);
    scatter_kernel<<<(CAP + 255) / 256, 256, 0, stream>>>(comp, meta, rankArr, sorted);
    gather_kernel<<<K_TOP / 4, 256, 0, stream>>>(sorted, preds, tboxes, tscores, tclass);
    mask_kernel<<<dim3(128, K_TOP / 256), 256, 0, stream>>>(tboxes, mask);
    valid_kernel<<<32, 256, 0, stream>>>(tscores, remw);
    nms_scan_kernel<<<1, 64, 0, stream>>>(mask, remw, tboxes, tscores, tclass, out);
}